// Round 1
// baseline (963.818 us; speedup 1.0000x reference)
//
#include <hip/hip_runtime.h>
#include <math.h>

// Problem constants (match reference)
#define NHID 128
#define NINP 128
#define NTD  64

#define TM 64     // nodes per block in GEMM kernels
#define KT 16     // K-tile

__device__ __forceinline__ float gelu_f(float v) {
    return 0.5f * v * (1.0f + erff(v * 0.70710678118654752440f));
}

// ---------------------------------------------------------------------------
// K0a: build combined first-layer weight Wc1 [320][256] from Wm1 [448][128].
//   input dims per node g = [s(128) | x(128) | t(64)]
//   output cols: [P(128) | Q(128)]
//   rows 0-127   (s): [Wa | Wb]
//   rows 128-255 (x): [Wc | -Wc]
//   rows 256-319 (t): [0  | Wd]
// where Wm1 = [Wa(0:128); Wb(128:256); Wc(256:384); Wd(384:448)]
// ---------------------------------------------------------------------------
__global__ void k_build_wc1(const float* __restrict__ Wm1, float* __restrict__ Wc1) {
    int idx = blockIdx.x * blockDim.x + threadIdx.x;   // 320*256 threads
    int r = idx >> 8, c = idx & 255;
    float v;
    if (r < 128) {
        v = (c < 128) ? Wm1[r * 128 + c] : Wm1[(128 + r) * 128 + (c - 128)];
    } else if (r < 256) {
        int rr = r - 128;
        v = (c < 128) ? Wm1[(256 + rr) * 128 + c] : -Wm1[(256 + rr) * 128 + (c - 128)];
    } else {
        int rr = r - 256;
        v = (c < 128) ? 0.0f : Wm1[(384 + rr) * 128 + (c - 128)];
    }
    Wc1[idx] = v;
}

// ---------------------------------------------------------------------------
// K0b: build combined update weight Wuc [256][128]:
//   rows 0-127  = Wu1_top
//   rows 128-255 = Wm2 @ Wu1_bot   (folds message layer 2 past the scatter)
// and bvec[c] = bm2 @ Wu1_bot
// ---------------------------------------------------------------------------
__global__ void k_build_wuc(const float* __restrict__ Wu1, const float* __restrict__ Wm2,
                            const float* __restrict__ bm2, float* __restrict__ Wuc,
                            float* __restrict__ bvec) {
    int idx = blockIdx.x * blockDim.x + threadIdx.x;   // 256*128 threads
    int r = idx >> 7, c = idx & 127;
    if (r < 128) {
        Wuc[idx] = Wu1[idx];
    } else {
        int i = r - 128;
        float acc = 0.f;
        for (int k = 0; k < 128; ++k) acc += Wm2[i * 128 + k] * Wu1[(128 + k) * 128 + c];
        Wuc[idx] = acc;
    }
    if (idx < 128) {
        float acc = 0.f;
        for (int k = 0; k < 128; ++k) acc += bm2[k] * Wu1[(128 + k) * 128 + idx];
        bvec[idx] = acc;
    }
}

// ---------------------------------------------------------------------------
// K1: node precompute. [P|Q] = g @ Wc1  (g = [s|x|t], K=320, out 256 cols)
// Also zeroes gagg and sw for this block's node range (needed every call).
// Register-tiled: 64 nodes x 256 cols per block, 256 threads, 4x16 per thread.
// Thread cols are STRIDED: c = tn*4 + 64*j (j=0..3) -> conflict-free b128 LDS reads.
// ---------------------------------------------------------------------------
__global__ __launch_bounds__(256) void k1_node_pre(
    const float* __restrict__ s, const float* __restrict__ x, const float* __restrict__ t,
    const float* __restrict__ Wc1, const float* __restrict__ bm1,
    float* __restrict__ P, float* __restrict__ Q,
    float* __restrict__ gagg, float* __restrict__ sw, int N)
{
    __shared__ float At[KT][TM + 4];
    __shared__ float Bt[KT][256];
    int tid = threadIdx.x;
    int n0 = blockIdx.x * TM;
    int nodes = N - n0; if (nodes > TM) nodes = TM;

    // zero gagg / sw for this node range (scatter targets for K2)
    {
        float4 z = make_float4(0.f, 0.f, 0.f, 0.f);
        float4* g4 = (float4*)(gagg + (size_t)n0 * NHID);
        int cnt4 = nodes * (NHID / 4);
        for (int i = tid; i < cnt4; i += 256) g4[i] = z;
        for (int i = tid; i < nodes; i += 256) sw[n0 + i] = 0.f;
    }

    int tm = tid >> 4;          // 0..15 -> nodes tm*4..+3
    int tn = tid & 15;          // cols tn*4 + 64*j
    int lkk = tid & 15;
    int lm  = (tid >> 4) * 4;

    float acc[4][16];
    #pragma unroll
    for (int i = 0; i < 4; ++i)
        #pragma unroll
        for (int j = 0; j < 16; ++j) acc[i][j] = 0.f;

    for (int k0 = 0; k0 < 320; k0 += KT) {
        // A tile (transposed in LDS: At[k][m])
        #pragma unroll
        for (int i = 0; i < 4; ++i) {
            int node = n0 + lm + i;
            int k = k0 + lkk;
            float v = 0.f;
            if (node < N) {
                if (k < 128)      v = s[(size_t)node * 128 + k];
                else if (k < 256) v = x[(size_t)node * 128 + (k - 128)];
                else              v = t[(size_t)node * 64 + (k - 256)];
            }
            At[lkk][lm + i] = v;
        }
        // B tile: 16 x 256 floats, coalesced float4
        {
            const float4* src4 = (const float4*)(Wc1 + (size_t)k0 * 256);
            float4* dst4 = (float4*)(&Bt[0][0]);
            #pragma unroll
            for (int i = 0; i < 4; ++i) dst4[tid + i * 256] = src4[tid + i * 256];
        }
        __syncthreads();
        #pragma unroll
        for (int kk = 0; kk < KT; ++kk) {
            float4 av = *(const float4*)&At[kk][tm * 4];
            float a0 = av.x, a1 = av.y, a2 = av.z, a3 = av.w;
            #pragma unroll
            for (int j = 0; j < 4; ++j) {
                float4 bv = *(const float4*)&Bt[kk][tn * 4 + 64 * j];
                acc[0][j*4+0] += a0*bv.x; acc[0][j*4+1] += a0*bv.y; acc[0][j*4+2] += a0*bv.z; acc[0][j*4+3] += a0*bv.w;
                acc[1][j*4+0] += a1*bv.x; acc[1][j*4+1] += a1*bv.y; acc[1][j*4+2] += a1*bv.z; acc[1][j*4+3] += a1*bv.w;
                acc[2][j*4+0] += a2*bv.x; acc[2][j*4+1] += a2*bv.y; acc[2][j*4+2] += a2*bv.z; acc[2][j*4+3] += a2*bv.w;
                acc[3][j*4+0] += a3*bv.x; acc[3][j*4+1] += a3*bv.y; acc[3][j*4+2] += a3*bv.z; acc[3][j*4+3] += a3*bv.w;
            }
        }
        __syncthreads();
    }

    // epilogue: cols < 128 -> P ; cols >= 128 -> Q (+ bm1 folded in)
    #pragma unroll
    for (int i = 0; i < 4; ++i) {
        int node = n0 + tm * 4 + i;
        if (node < N) {
            #pragma unroll
            for (int j = 0; j < 4; ++j) {
                int cbase = tn * 4 + 64 * j;
                float4 v = make_float4(acc[i][j*4+0], acc[i][j*4+1], acc[i][j*4+2], acc[i][j*4+3]);
                if (j < 2) {
                    *(float4*)&P[(size_t)node * 128 + cbase] = v;
                } else {
                    int qc = cbase - 128;
                    float4 bb = *(const float4*)&bm1[qc];
                    v.x += bb.x; v.y += bb.y; v.z += bb.z; v.w += bb.w;
                    *(float4*)&Q[(size_t)node * 128 + qc] = v;
                }
            }
        }
    }
}

// ---------------------------------------------------------------------------
// K2: edge kernel. One wave (64 lanes) per edge, 2 channels per lane.
//   h = gelu(P[src] + Q[dst]);  gagg[dst] += w*h ;  sw[dst] += w
// ---------------------------------------------------------------------------
__global__ __launch_bounds__(256) void k2_edge(
    const float* __restrict__ P, const float* __restrict__ Q,
    const int* __restrict__ srcI, const int* __restrict__ dstI,
    const float* __restrict__ w, float* __restrict__ gagg,
    float* __restrict__ sw, int E)
{
    int e = blockIdx.x * 4 + (threadIdx.x >> 6);
    if (e >= E) return;
    int lane = threadIdx.x & 63;
    int sN = srcI[e];
    int dN = dstI[e];
    float we = w[e];
    float2 p = *(const float2*)&P[(size_t)sN * 128 + lane * 2];
    float2 q = *(const float2*)&Q[(size_t)dN * 128 + lane * 2];
    float h0 = gelu_f(p.x + q.x) * we;
    float h1 = gelu_f(p.y + q.y) * we;
    atomicAdd(&gagg[(size_t)dN * 128 + lane * 2 + 0], h0);
    atomicAdd(&gagg[(size_t)dN * 128 + lane * 2 + 1], h1);
    if (lane == 0) atomicAdd(&sw[dN], we);
}

// ---------------------------------------------------------------------------
// K3: update MLP, fused two layers per 64-node block.
//   pre2 = [s|gagg] @ Wuc + sw*bvec + bu1 ; h2 = gelu(pre2)
//   out  = h2 @ Wu2 + bu2
// ---------------------------------------------------------------------------
__global__ __launch_bounds__(256) void k3_update(
    const float* __restrict__ s, const float* __restrict__ gagg, const float* __restrict__ sw,
    const float* __restrict__ Wuc, const float* __restrict__ bvec, const float* __restrict__ bu1,
    const float* __restrict__ Wu2, const float* __restrict__ bu2,
    float* __restrict__ out, int N)
{
    __shared__ float At[KT][TM + 4];
    __shared__ float Bt[KT][128];
    __shared__ float h2T[128][TM + 4];   // transposed gelu output
    int tid = threadIdx.x;
    int n0 = blockIdx.x * TM;
    int tm = tid >> 4, tn = tid & 15;
    int lkk = tid & 15, lm = (tid >> 4) * 4;

    float acc[4][8];
    #pragma unroll
    for (int i = 0; i < 4; ++i)
        #pragma unroll
        for (int j = 0; j < 8; ++j) acc[i][j] = 0.f;

    // Phase A: pre2 = [s|gagg] @ Wuc  (K = 256, 128 cols)
    for (int k0 = 0; k0 < 256; k0 += KT) {
        #pragma unroll
        for (int i = 0; i < 4; ++i) {
            int node = n0 + lm + i;
            int k = k0 + lkk;
            float v = 0.f;
            if (node < N)
                v = (k < 128) ? s[(size_t)node * 128 + k] : gagg[(size_t)node * 128 + (k - 128)];
            At[lkk][lm + i] = v;
        }
        {
            const float4* src4 = (const float4*)(Wuc + (size_t)k0 * 128);
            float4* dst4 = (float4*)(&Bt[0][0]);
            dst4[tid] = src4[tid];
            dst4[tid + 256] = src4[tid + 256];
        }
        __syncthreads();
        #pragma unroll
        for (int kk = 0; kk < KT; ++kk) {
            float4 av = *(const float4*)&At[kk][tm * 4];
            float a0 = av.x, a1 = av.y, a2 = av.z, a3 = av.w;
            #pragma unroll
            for (int j = 0; j < 2; ++j) {
                float4 bv = *(const float4*)&Bt[kk][tn * 4 + 64 * j];
                acc[0][j*4+0] += a0*bv.x; acc[0][j*4+1] += a0*bv.y; acc[0][j*4+2] += a0*bv.z; acc[0][j*4+3] += a0*bv.w;
                acc[1][j*4+0] += a1*bv.x; acc[1][j*4+1] += a1*bv.y; acc[1][j*4+2] += a1*bv.z; acc[1][j*4+3] += a1*bv.w;
                acc[2][j*4+0] += a2*bv.x; acc[2][j*4+1] += a2*bv.y; acc[2][j*4+2] += a2*bv.z; acc[2][j*4+3] += a2*bv.w;
                acc[3][j*4+0] += a3*bv.x; acc[3][j*4+1] += a3*bv.y; acc[3][j*4+2] += a3*bv.z; acc[3][j*4+3] += a3*bv.w;
            }
        }
        __syncthreads();
    }

    // epilogue A: bias + sw*bvec + gelu, write transposed to LDS
    float swv[4];
    #pragma unroll
    for (int i = 0; i < 4; ++i) {
        int node = n0 + tm * 4 + i;
        swv[i] = (node < N) ? sw[node] : 0.f;
    }
    #pragma unroll
    for (int i = 0; i < 4; ++i) {
        #pragma unroll
        for (int j = 0; j < 2; ++j) {
            #pragma unroll
            for (int jj = 0; jj < 4; ++jj) {
                int c = tn * 4 + 64 * j + jj;
                float v = acc[i][j * 4 + jj] + bu1[c] + swv[i] * bvec[c];
                h2T[c][tm * 4 + i] = gelu_f(v);
            }
        }
    }
    __syncthreads();

    // Phase B: out = h2 @ Wu2 + bu2 (K = 128)
    float acc2[4][8];
    #pragma unroll
    for (int i = 0; i < 4; ++i)
        #pragma unroll
        for (int j = 0; j < 8; ++j) acc2[i][j] = 0.f;

    for (int k0 = 0; k0 < 128; k0 += KT) {
        {
            const float4* src4 = (const float4*)(Wu2 + (size_t)k0 * 128);
            float4* dst4 = (float4*)(&Bt[0][0]);
            dst4[tid] = src4[tid];
            dst4[tid + 256] = src4[tid + 256];
        }
        __syncthreads();
        #pragma unroll
        for (int kk = 0; kk < KT; ++kk) {
            float4 av = *(const float4*)&h2T[k0 + kk][tm * 4];
            float a0 = av.x, a1 = av.y, a2 = av.z, a3 = av.w;
            #pragma unroll
            for (int j = 0; j < 2; ++j) {
                float4 bv = *(const float4*)&Bt[kk][tn * 4 + 64 * j];
                acc2[0][j*4+0] += a0*bv.x; acc2[0][j*4+1] += a0*bv.y; acc2[0][j*4+2] += a0*bv.z; acc2[0][j*4+3] += a0*bv.w;
                acc2[1][j*4+0] += a1*bv.x; acc2[1][j*4+1] += a1*bv.y; acc2[1][j*4+2] += a1*bv.z; acc2[1][j*4+3] += a1*bv.w;
                acc2[2][j*4+0] += a2*bv.x; acc2[2][j*4+1] += a2*bv.y; acc2[2][j*4+2] += a2*bv.z; acc2[2][j*4+3] += a2*bv.w;
                acc2[3][j*4+0] += a3*bv.x; acc2[3][j*4+1] += a3*bv.y; acc2[3][j*4+2] += a3*bv.z; acc2[3][j*4+3] += a3*bv.w;
            }
        }
        __syncthreads();
    }

    #pragma unroll
    for (int i = 0; i < 4; ++i) {
        int node = n0 + tm * 4 + i;
        if (node < N) {
            #pragma unroll
            for (int j = 0; j < 2; ++j) {
                int c = tn * 4 + 64 * j;
                float4 bb = *(const float4*)&bu2[c];
                float4 v = make_float4(acc2[i][j*4+0] + bb.x, acc2[i][j*4+1] + bb.y,
                                       acc2[i][j*4+2] + bb.z, acc2[i][j*4+3] + bb.w);
                *(float4*)&out[(size_t)node * 128 + c] = v;
            }
        }
    }
}

// ---------------------------------------------------------------------------
extern "C" void kernel_launch(void* const* d_in, const int* in_sizes, int n_in,
                              void* d_out, int out_size, void* d_ws, size_t ws_size,
                              hipStream_t stream) {
    const float* s    = (const float*)d_in[0];
    const float* x    = (const float*)d_in[1];
    const int*   ei   = (const int*)d_in[2];
    const float* ew   = (const float*)d_in[3];
    const float* t    = (const float*)d_in[4];
    const float* Wm1  = (const float*)d_in[5];
    const float* bm1  = (const float*)d_in[6];
    const float* Wm2  = (const float*)d_in[7];
    const float* bm2  = (const float*)d_in[8];
    const float* Wu1  = (const float*)d_in[9];
    const float* bu1  = (const float*)d_in[10];
    const float* Wu2  = (const float*)d_in[11];
    const float* bu2  = (const float*)d_in[12];

    int N = in_sizes[0] / 128;
    int E = in_sizes[2] / 2;

    // workspace layout (floats); total ~77.5 MB
    float* ws = (float*)d_ws;
    size_t off = 0;
    float* P   = ws + off; off += (size_t)N * 128;
    float* Q   = ws + off; off += (size_t)N * 128;
    float* G   = ws + off; off += (size_t)N * 128;
    float* SW  = ws + off; off += ((size_t)N + 63) & ~(size_t)63;
    float* WC1 = ws + off; off += 320 * 256;
    float* WUC = ws + off; off += 256 * 128;
    float* BV  = ws + off; off += 128;

    k_build_wc1<<<(320 * 256) / 256, 256, 0, stream>>>(Wm1, WC1);
    k_build_wuc<<<(256 * 128) / 256, 256, 0, stream>>>(Wu1, Wm2, bm2, WUC, BV);

    int nb = (N + TM - 1) / TM;
    k1_node_pre<<<nb, 256, 0, stream>>>(s, x, t, WC1, bm1, P, Q, G, SW, N);
    k2_edge<<<(E + 3) / 4, 256, 0, stream>>>(P, Q, ei, ei + E, ew, G, SW, E);
    k3_update<<<nb, 256, 0, stream>>>(s, G, SW, WUC, BV, bu1, Wu2, bu2, (float*)d_out, N);
}

// Round 2
// 486.325 us; speedup vs baseline: 1.9818x; 1.9818x over previous
//
#include <hip/hip_runtime.h>
#include <math.h>

// Problem constants (match reference)
#define NHID 128
#define NINP 128
#define NTD  64

#define TM 64     // nodes per block in GEMM kernels
#define KT 16     // K-tile

__device__ __forceinline__ float gelu_f(float v) {
    return 0.5f * v * (1.0f + erff(v * 0.70710678118654752440f));
}

// ---------------------------------------------------------------------------
// K0a: build combined first-layer weight Wc1 [320][256] from Wm1 [448][128].
//   input dims per node g = [s(128) | x(128) | t(64)]
//   output cols: [P(128) | Q(128)]
//   rows 0-127   (s): [Wa | Wb]
//   rows 128-255 (x): [Wc | -Wc]
//   rows 256-319 (t): [0  | Wd]
// ---------------------------------------------------------------------------
__global__ void k_build_wc1(const float* __restrict__ Wm1, float* __restrict__ Wc1) {
    int idx = blockIdx.x * blockDim.x + threadIdx.x;   // 320*256 threads
    int r = idx >> 8, c = idx & 255;
    float v;
    if (r < 128) {
        v = (c < 128) ? Wm1[r * 128 + c] : Wm1[(128 + r) * 128 + (c - 128)];
    } else if (r < 256) {
        int rr = r - 128;
        v = (c < 128) ? Wm1[(256 + rr) * 128 + c] : -Wm1[(256 + rr) * 128 + (c - 128)];
    } else {
        int rr = r - 256;
        v = (c < 128) ? 0.0f : Wm1[(384 + rr) * 128 + (c - 128)];
    }
    Wc1[idx] = v;
}

// ---------------------------------------------------------------------------
// K0b: build combined update weight Wuc [256][128]:
//   rows 0-127   = Wu1_top
//   rows 128-255 = Wm2 @ Wu1_bot   (folds message layer 2 past the scatter)
// and bvec[c] = bm2 @ Wu1_bot
// ---------------------------------------------------------------------------
__global__ void k_build_wuc(const float* __restrict__ Wu1, const float* __restrict__ Wm2,
                            const float* __restrict__ bm2, float* __restrict__ Wuc,
                            float* __restrict__ bvec) {
    int idx = blockIdx.x * blockDim.x + threadIdx.x;   // 256*128 threads
    int r = idx >> 7, c = idx & 127;
    if (r < 128) {
        Wuc[idx] = Wu1[idx];
    } else {
        int i = r - 128;
        float acc = 0.f;
        for (int k = 0; k < 128; ++k) acc += Wm2[i * 128 + k] * Wu1[(128 + k) * 128 + c];
        Wuc[idx] = acc;
    }
    if (idx < 128) {
        float acc = 0.f;
        for (int k = 0; k < 128; ++k) acc += bm2[k] * Wu1[(128 + k) * 128 + idx];
        bvec[idx] = acc;
    }
}

// ---------------------------------------------------------------------------
// Counting-sort pipeline: zero -> histogram -> scan -> scatter
// ---------------------------------------------------------------------------
__global__ void k_zero_i(int* __restrict__ p, int n) {
    int i = blockIdx.x * blockDim.x + threadIdx.x;
    if (i < n) p[i] = 0;
}

__global__ void k_hist(const int* __restrict__ dst, int* __restrict__ deg, int E) {
    int i = blockIdx.x * blockDim.x + threadIdx.x;
    if (i < E) atomicAdd(&deg[dst[i]], 1);
}

// single-block exclusive scan over N degrees -> offs[0..N], cursor copy
__global__ __launch_bounds__(1024) void k_scan(const int* __restrict__ deg,
                                               int* __restrict__ offs,
                                               int* __restrict__ cursor, int N, int E) {
    __shared__ int wsum[17];          // [16] holds the running carry
    int tid = threadIdx.x;
    int lane = tid & 63, wid = tid >> 6;
    if (tid == 0) wsum[16] = 0;
    __syncthreads();
    for (int base = 0; base < N; base += 1024) {
        int i = base + tid;
        int v = (i < N) ? deg[i] : 0;
        int incl = v;
        #pragma unroll
        for (int d = 1; d < 64; d <<= 1) {
            int t = __shfl_up(incl, d);
            if (lane >= d) incl += t;
        }
        if (lane == 63) wsum[wid] = incl;
        __syncthreads();
        if (tid == 0) {
            int run = wsum[16];
            #pragma unroll
            for (int k = 0; k < 16; ++k) { int t = wsum[k]; wsum[k] = run; run += t; }
            wsum[16] = run;
        }
        __syncthreads();
        int excl = wsum[wid] + incl - v;
        if (i < N) { offs[i] = excl; cursor[i] = excl; }
        __syncthreads();
    }
    if (tid == 0) offs[N] = E;
}

__global__ void k_scatter(const int* __restrict__ src, const int* __restrict__ dst,
                          const float* __restrict__ w, int* __restrict__ cursor,
                          int2* __restrict__ rec, int E) {
    int i = blockIdx.x * blockDim.x + threadIdx.x;
    if (i < E) {
        int d = dst[i];
        int pos = atomicAdd(&cursor[d], 1);
        rec[pos] = make_int2(src[i], __float_as_int(w[i]));
    }
}

// ---------------------------------------------------------------------------
// K1: node precompute. [P|Q] = g @ Wc1  (g = [s|x|t], K=320, out 256 cols)
// Register-tiled: 64 nodes x 256 cols per block, 256 threads, 4x16 per thread.
// ---------------------------------------------------------------------------
__global__ __launch_bounds__(256) void k1_node_pre(
    const float* __restrict__ s, const float* __restrict__ x, const float* __restrict__ t,
    const float* __restrict__ Wc1, const float* __restrict__ bm1,
    float* __restrict__ P, float* __restrict__ Q, int N)
{
    __shared__ float At[KT][TM + 4];
    __shared__ float Bt[KT][256];
    int tid = threadIdx.x;
    int n0 = blockIdx.x * TM;

    int tm = tid >> 4;          // 0..15 -> nodes tm*4..+3
    int tn = tid & 15;          // cols tn*4 + 64*j
    int lkk = tid & 15;
    int lm  = (tid >> 4) * 4;

    float acc[4][16];
    #pragma unroll
    for (int i = 0; i < 4; ++i)
        #pragma unroll
        for (int j = 0; j < 16; ++j) acc[i][j] = 0.f;

    for (int k0 = 0; k0 < 320; k0 += KT) {
        #pragma unroll
        for (int i = 0; i < 4; ++i) {
            int node = n0 + lm + i;
            int k = k0 + lkk;
            float v = 0.f;
            if (node < N) {
                if (k < 128)      v = s[(size_t)node * 128 + k];
                else if (k < 256) v = x[(size_t)node * 128 + (k - 128)];
                else              v = t[(size_t)node * 64 + (k - 256)];
            }
            At[lkk][lm + i] = v;
        }
        {
            const float4* src4 = (const float4*)(Wc1 + (size_t)k0 * 256);
            float4* dst4 = (float4*)(&Bt[0][0]);
            #pragma unroll
            for (int i = 0; i < 4; ++i) dst4[tid + i * 256] = src4[tid + i * 256];
        }
        __syncthreads();
        #pragma unroll
        for (int kk = 0; kk < KT; ++kk) {
            float4 av = *(const float4*)&At[kk][tm * 4];
            float a0 = av.x, a1 = av.y, a2 = av.z, a3 = av.w;
            #pragma unroll
            for (int j = 0; j < 4; ++j) {
                float4 bv = *(const float4*)&Bt[kk][tn * 4 + 64 * j];
                acc[0][j*4+0] += a0*bv.x; acc[0][j*4+1] += a0*bv.y; acc[0][j*4+2] += a0*bv.z; acc[0][j*4+3] += a0*bv.w;
                acc[1][j*4+0] += a1*bv.x; acc[1][j*4+1] += a1*bv.y; acc[1][j*4+2] += a1*bv.z; acc[1][j*4+3] += a1*bv.w;
                acc[2][j*4+0] += a2*bv.x; acc[2][j*4+1] += a2*bv.y; acc[2][j*4+2] += a2*bv.z; acc[2][j*4+3] += a2*bv.w;
                acc[3][j*4+0] += a3*bv.x; acc[3][j*4+1] += a3*bv.y; acc[3][j*4+2] += a3*bv.z; acc[3][j*4+3] += a3*bv.w;
            }
        }
        __syncthreads();
    }

    #pragma unroll
    for (int i = 0; i < 4; ++i) {
        int node = n0 + tm * 4 + i;
        if (node < N) {
            #pragma unroll
            for (int j = 0; j < 4; ++j) {
                int cbase = tn * 4 + 64 * j;
                float4 v = make_float4(acc[i][j*4+0], acc[i][j*4+1], acc[i][j*4+2], acc[i][j*4+3]);
                if (j < 2) {
                    *(float4*)&P[(size_t)node * 128 + cbase] = v;
                } else {
                    int qc = cbase - 128;
                    float4 bb = *(const float4*)&bm1[qc];
                    v.x += bb.x; v.y += bb.y; v.z += bb.z; v.w += bb.w;
                    *(float4*)&Q[(size_t)node * 128 + qc] = v;
                }
            }
        }
    }
}

// ---------------------------------------------------------------------------
// K_agg: segmented reduction over dst-sorted edges. One wave per dst node,
// 2 channels per lane. Q row in registers; gather P[src] per edge; accumulate
// in registers; single plain store per node. NO atomics.
// ---------------------------------------------------------------------------
__global__ __launch_bounds__(256) void k_agg(
    const float* __restrict__ P, const float* __restrict__ Q,
    const int2* __restrict__ rec, const int* __restrict__ offs,
    float* __restrict__ gagg, float* __restrict__ sw, int N)
{
    int n = blockIdx.x * 4 + (threadIdx.x >> 6);
    if (n >= N) return;
    int lane = threadIdx.x & 63;
    int beg = offs[n], end = offs[n + 1];
    float2 q = *(const float2*)&Q[(size_t)n * 128 + lane * 2];
    float a0 = 0.f, a1 = 0.f, wsum = 0.f;
    for (int base = beg; base < end; base += 64) {
        int cnt = end - base; if (cnt > 64) cnt = 64;
        int2 r = make_int2(0, 0);
        if (lane < cnt) r = rec[base + lane];
        for (int j = 0; j < cnt; ++j) {
            int  sidx = __shfl(r.x, j);
            float wj  = __int_as_float(__shfl(r.y, j));
            float2 p  = *(const float2*)&P[(size_t)sidx * 128 + lane * 2];
            a0 += wj * gelu_f(p.x + q.x);
            a1 += wj * gelu_f(p.y + q.y);
            wsum += wj;
        }
    }
    *(float2*)&gagg[(size_t)n * 128 + lane * 2] = make_float2(a0, a1);
    if (lane == 0) sw[n] = wsum;
}

// ---------------------------------------------------------------------------
// K3: update MLP, fused two layers per 64-node block.
//   pre2 = [s|gagg] @ Wuc + sw*bvec + bu1 ; h2 = gelu(pre2)
//   out  = h2 @ Wu2 + bu2
// ---------------------------------------------------------------------------
__global__ __launch_bounds__(256) void k3_update(
    const float* __restrict__ s, const float* __restrict__ gagg, const float* __restrict__ sw,
    const float* __restrict__ Wuc, const float* __restrict__ bvec, const float* __restrict__ bu1,
    const float* __restrict__ Wu2, const float* __restrict__ bu2,
    float* __restrict__ out, int N)
{
    __shared__ float At[KT][TM + 4];
    __shared__ float Bt[KT][128];
    __shared__ float h2T[128][TM + 4];   // transposed gelu output
    int tid = threadIdx.x;
    int n0 = blockIdx.x * TM;
    int tm = tid >> 4, tn = tid & 15;
    int lkk = tid & 15, lm = (tid >> 4) * 4;

    float acc[4][8];
    #pragma unroll
    for (int i = 0; i < 4; ++i)
        #pragma unroll
        for (int j = 0; j < 8; ++j) acc[i][j] = 0.f;

    // Phase A: pre2 = [s|gagg] @ Wuc  (K = 256, 128 cols)
    for (int k0 = 0; k0 < 256; k0 += KT) {
        #pragma unroll
        for (int i = 0; i < 4; ++i) {
            int node = n0 + lm + i;
            int k = k0 + lkk;
            float v = 0.f;
            if (node < N)
                v = (k < 128) ? s[(size_t)node * 128 + k] : gagg[(size_t)node * 128 + (k - 128)];
            At[lkk][lm + i] = v;
        }
        {
            const float4* src4 = (const float4*)(Wuc + (size_t)k0 * 128);
            float4* dst4 = (float4*)(&Bt[0][0]);
            dst4[tid] = src4[tid];
            dst4[tid + 256] = src4[tid + 256];
        }
        __syncthreads();
        #pragma unroll
        for (int kk = 0; kk < KT; ++kk) {
            float4 av = *(const float4*)&At[kk][tm * 4];
            float a0 = av.x, a1 = av.y, a2 = av.z, a3 = av.w;
            #pragma unroll
            for (int j = 0; j < 2; ++j) {
                float4 bv = *(const float4*)&Bt[kk][tn * 4 + 64 * j];
                acc[0][j*4+0] += a0*bv.x; acc[0][j*4+1] += a0*bv.y; acc[0][j*4+2] += a0*bv.z; acc[0][j*4+3] += a0*bv.w;
                acc[1][j*4+0] += a1*bv.x; acc[1][j*4+1] += a1*bv.y; acc[1][j*4+2] += a1*bv.z; acc[1][j*4+3] += a1*bv.w;
                acc[2][j*4+0] += a2*bv.x; acc[2][j*4+1] += a2*bv.y; acc[2][j*4+2] += a2*bv.z; acc[2][j*4+3] += a2*bv.w;
                acc[3][j*4+0] += a3*bv.x; acc[3][j*4+1] += a3*bv.y; acc[3][j*4+2] += a3*bv.z; acc[3][j*4+3] += a3*bv.w;
            }
        }
        __syncthreads();
    }

    // epilogue A: bias + sw*bvec + gelu, write transposed to LDS
    float swv[4];
    #pragma unroll
    for (int i = 0; i < 4; ++i) {
        int node = n0 + tm * 4 + i;
        swv[i] = (node < N) ? sw[node] : 0.f;
    }
    #pragma unroll
    for (int i = 0; i < 4; ++i) {
        #pragma unroll
        for (int j = 0; j < 2; ++j) {
            #pragma unroll
            for (int jj = 0; jj < 4; ++jj) {
                int c = tn * 4 + 64 * j + jj;
                float v = acc[i][j * 4 + jj] + bu1[c] + swv[i] * bvec[c];
                h2T[c][tm * 4 + i] = gelu_f(v);
            }
        }
    }
    __syncthreads();

    // Phase B: out = h2 @ Wu2 + bu2 (K = 128)
    float acc2[4][8];
    #pragma unroll
    for (int i = 0; i < 4; ++i)
        #pragma unroll
        for (int j = 0; j < 8; ++j) acc2[i][j] = 0.f;

    for (int k0 = 0; k0 < 128; k0 += KT) {
        {
            const float4* src4 = (const float4*)(Wu2 + (size_t)k0 * 128);
            float4* dst4 = (float4*)(&Bt[0][0]);
            dst4[tid] = src4[tid];
            dst4[tid + 256] = src4[tid + 256];
        }
        __syncthreads();
        #pragma unroll
        for (int kk = 0; kk < KT; ++kk) {
            float4 av = *(const float4*)&h2T[k0 + kk][tm * 4];
            float a0 = av.x, a1 = av.y, a2 = av.z, a3 = av.w;
            #pragma unroll
            for (int j = 0; j < 2; ++j) {
                float4 bv = *(const float4*)&Bt[kk][tn * 4 + 64 * j];
                acc2[0][j*4+0] += a0*bv.x; acc2[0][j*4+1] += a0*bv.y; acc2[0][j*4+2] += a0*bv.z; acc2[0][j*4+3] += a0*bv.w;
                acc2[1][j*4+0] += a1*bv.x; acc2[1][j*4+1] += a1*bv.y; acc2[1][j*4+2] += a1*bv.z; acc2[1][j*4+3] += a1*bv.w;
                acc2[2][j*4+0] += a2*bv.x; acc2[2][j*4+1] += a2*bv.y; acc2[2][j*4+2] += a2*bv.z; acc2[2][j*4+3] += a2*bv.w;
                acc2[3][j*4+0] += a3*bv.x; acc2[3][j*4+1] += a3*bv.y; acc2[3][j*4+2] += a3*bv.z; acc2[3][j*4+3] += a3*bv.w;
            }
        }
        __syncthreads();
    }

    #pragma unroll
    for (int i = 0; i < 4; ++i) {
        int node = n0 + tm * 4 + i;
        if (node < N) {
            #pragma unroll
            for (int j = 0; j < 2; ++j) {
                int c = tn * 4 + 64 * j;
                float4 bb = *(const float4*)&bu2[c];
                float4 v = make_float4(acc2[i][j*4+0] + bb.x, acc2[i][j*4+1] + bb.y,
                                       acc2[i][j*4+2] + bb.z, acc2[i][j*4+3] + bb.w);
                *(float4*)&out[(size_t)node * 128 + c] = v;
            }
        }
    }
}

// ---------------------------------------------------------------------------
extern "C" void kernel_launch(void* const* d_in, const int* in_sizes, int n_in,
                              void* d_out, int out_size, void* d_ws, size_t ws_size,
                              hipStream_t stream) {
    const float* s    = (const float*)d_in[0];
    const float* x    = (const float*)d_in[1];
    const int*   ei   = (const int*)d_in[2];
    const float* ew   = (const float*)d_in[3];
    const float* t    = (const float*)d_in[4];
    const float* Wm1  = (const float*)d_in[5];
    const float* bm1  = (const float*)d_in[6];
    const float* Wm2  = (const float*)d_in[7];
    const float* bm2  = (const float*)d_in[8];
    const float* Wu1  = (const float*)d_in[9];
    const float* bu1  = (const float*)d_in[10];
    const float* Wu2  = (const float*)d_in[11];
    const float* bu2  = (const float*)d_in[12];

    int N = in_sizes[0] / 128;
    int E = in_sizes[2] / 2;
    const int* srcI = ei;
    const int* dstI = ei + E;

    // workspace layout (32-bit words); total ~85 MB
    float* ws = (float*)d_ws;
    size_t off = 0;
    float* P    = ws + off; off += (size_t)N * 128;
    float* Q    = ws + off; off += (size_t)N * 128;
    float* G    = ws + off; off += (size_t)N * 128;
    float* SW   = ws + off; off += ((size_t)N + 63) & ~(size_t)63;
    float* WC1  = ws + off; off += 320 * 256;
    float* WUC  = ws + off; off += 256 * 128;
    float* BV   = ws + off; off += 128;
    int*   DEG  = (int*)(ws + off); off += (size_t)N;
    int*   OFFS = (int*)(ws + off); off += (size_t)N + 64;
    int*   CUR  = (int*)(ws + off); off += (size_t)N;
    off = (off + 1) & ~(size_t)1;          // 8B align for int2
    int2*  REC  = (int2*)(ws + off); off += (size_t)E * 2;

    // weight prep (independent of edge pipeline)
    k_build_wc1<<<(320 * 256) / 256, 256, 0, stream>>>(Wm1, WC1);
    k_build_wuc<<<(256 * 128) / 256, 256, 0, stream>>>(Wu1, Wm2, bm2, WUC, BV);

    // counting sort by dst
    k_zero_i<<<(N + 255) / 256, 256, 0, stream>>>(DEG, N);
    k_hist<<<(E + 255) / 256, 256, 0, stream>>>(dstI, DEG, E);
    k_scan<<<1, 1024, 0, stream>>>(DEG, OFFS, CUR, N, E);
    k_scatter<<<(E + 255) / 256, 256, 0, stream>>>(srcI, dstI, ew, CUR, REC, E);

    // node precompute
    int nb = (N + TM - 1) / TM;
    k1_node_pre<<<nb, 256, 0, stream>>>(s, x, t, WC1, bm1, P, Q, N);

    // segmented aggregation (no atomics)
    k_agg<<<(N + 3) / 4, 256, 0, stream>>>(P, Q, REC, OFFS, G, SW, N);

    // update MLP
    k3_update<<<nb, 256, 0, stream>>>(s, G, SW, WUC, BV, bu1, Wu2, bu2, (float*)d_out, N);
}

// Round 3
// 305.801 us; speedup vs baseline: 3.1518x; 1.5903x over previous
//
#include <hip/hip_runtime.h>
#include <math.h>

// Problem constants
#define NHID 128

typedef __attribute__((ext_vector_type(8))) short bf16x8;
typedef __attribute__((ext_vector_type(4))) float f32x4;

union BF8 { ushort u[8]; bf16x8 v; };

__device__ __forceinline__ float gelu_f(float v) {
    return 0.5f * v * (1.0f + erff(v * 0.70710678118654752440f));
}
__device__ __forceinline__ ushort f2bf(float f) {
    unsigned int u = __float_as_uint(f);
    u += 0x7FFFu + ((u >> 16) & 1u);      // round-to-nearest-even
    return (ushort)(u >> 16);
}
__device__ __forceinline__ float bf2f(ushort u) {
    return __uint_as_float(((unsigned int)u) << 16);
}

// ---------------------------------------------------------------------------
// Weight prep: all weights go to bf16, TRANSPOSED to [col][k] so MFMA B-frags
// are contiguous-8 along k (ds_read_b128).
// WC1T [256 cols][320 k]: combined first layer.
//   k 0-127 (s):   col<128 -> Wm1[k][c]        else Wm1[128+k][c-128]
//   k 128-255 (x): col<128 -> Wm1[256+kk][c]   else -Wm1[256+kk][c-128]
//   k 256-319 (t): col<128 -> 0                else Wm1[384+kk][c-128]
// ---------------------------------------------------------------------------
__global__ void k_build_wc1t(const float* __restrict__ Wm1, ushort* __restrict__ WC1T) {
    int idx = blockIdx.x * blockDim.x + threadIdx.x;   // 256*320
    int c = idx / 320, k = idx % 320;
    float v;
    if (k < 128) {
        v = (c < 128) ? Wm1[k * 128 + c] : Wm1[(128 + k) * 128 + (c - 128)];
    } else if (k < 256) {
        int kk = k - 128;
        v = (c < 128) ? Wm1[(256 + kk) * 128 + c] : -Wm1[(256 + kk) * 128 + (c - 128)];
    } else {
        int kk = k - 256;
        v = (c < 128) ? 0.0f : Wm1[(384 + kk) * 128 + (c - 128)];
    }
    WC1T[idx] = f2bf(v);
}

// WUCT [128 cols][256 k]: k<128 -> Wu1_top[k][c]; k>=128 -> (Wm2 @ Wu1_bot)[k-128][c]
// BV[c] = bm2 @ Wu1_bot (fp32)
__global__ void k_build_wuct(const float* __restrict__ Wu1, const float* __restrict__ Wm2,
                             const float* __restrict__ bm2, ushort* __restrict__ WUCT,
                             float* __restrict__ BV) {
    int idx = blockIdx.x * blockDim.x + threadIdx.x;   // 128*256
    int c = idx >> 8, k = idx & 255;
    float v;
    if (k < 128) {
        v = Wu1[k * 128 + c];
    } else {
        int i = k - 128;
        float acc = 0.f;
        for (int j = 0; j < 128; ++j) acc += Wm2[i * 128 + j] * Wu1[(128 + j) * 128 + c];
        v = acc;
    }
    WUCT[idx] = f2bf(v);
    if (idx < 128) {
        float acc = 0.f;
        for (int j = 0; j < 128; ++j) acc += bm2[j] * Wu1[(128 + j) * 128 + idx];
        BV[idx] = acc;
    }
}

// WU2T [128 cols][128 k] = Wu2[k][c]
__global__ void k_build_wu2t(const float* __restrict__ Wu2, ushort* __restrict__ WU2T) {
    int idx = blockIdx.x * blockDim.x + threadIdx.x;   // 128*128
    int c = idx >> 7, k = idx & 127;
    WU2T[idx] = f2bf(Wu2[k * 128 + c]);
}

// ---------------------------------------------------------------------------
// Counting-sort pipeline (unchanged, verified)
// ---------------------------------------------------------------------------
__global__ void k_zero_i(int* __restrict__ p, int n) {
    int i = blockIdx.x * blockDim.x + threadIdx.x;
    if (i < n) p[i] = 0;
}
__global__ void k_hist(const int* __restrict__ dst, int* __restrict__ deg, int E) {
    int i = blockIdx.x * blockDim.x + threadIdx.x;
    if (i < E) atomicAdd(&deg[dst[i]], 1);
}
__global__ __launch_bounds__(1024) void k_scan(const int* __restrict__ deg,
                                               int* __restrict__ offs,
                                               int* __restrict__ cursor, int N, int E) {
    __shared__ int wsum[17];
    int tid = threadIdx.x;
    int lane = tid & 63, wid = tid >> 6;
    if (tid == 0) wsum[16] = 0;
    __syncthreads();
    for (int base = 0; base < N; base += 1024) {
        int i = base + tid;
        int v = (i < N) ? deg[i] : 0;
        int incl = v;
        #pragma unroll
        for (int d = 1; d < 64; d <<= 1) {
            int t = __shfl_up(incl, d);
            if (lane >= d) incl += t;
        }
        if (lane == 63) wsum[wid] = incl;
        __syncthreads();
        if (tid == 0) {
            int run = wsum[16];
            #pragma unroll
            for (int k = 0; k < 16; ++k) { int t = wsum[k]; wsum[k] = run; run += t; }
            wsum[16] = run;
        }
        __syncthreads();
        int excl = wsum[wid] + incl - v;
        if (i < N) { offs[i] = excl; cursor[i] = excl; }
        __syncthreads();
    }
    if (tid == 0) offs[N] = E;
}
__global__ void k_scatter(const int* __restrict__ src, const int* __restrict__ dst,
                          const float* __restrict__ w, int* __restrict__ cursor,
                          int2* __restrict__ rec, int E) {
    int i = blockIdx.x * blockDim.x + threadIdx.x;
    if (i < E) {
        int d = dst[i];
        int pos = atomicAdd(&cursor[d], 1);
        rec[pos] = make_int2(src[i], __float_as_int(w[i]));
    }
}

// ---------------------------------------------------------------------------
// K1 (MFMA): [P|Q] = [s|x|t] @ Wc1.  M=N, K=320, 256 out cols.
// Block: 256 thr = 4 waves; tile 64 rows x 256 cols; wave w owns cols w*64..+63.
// A staged fp32->bf16 into LDS [64][40] (pad 40 vs 32 to spread banks);
// B staged bf16 from WC1T into LDS [256][40].
// mfma_f32_16x16x32_bf16: A row=l&15,k=(l>>4)*8+j ; D col=l&15,row=(l>>4)*4+r.
// ---------------------------------------------------------------------------
__global__ __launch_bounds__(256) void k1_mfma(
    const float* __restrict__ s, const float* __restrict__ x, const float* __restrict__ t,
    const ushort* __restrict__ WC1T, const float* __restrict__ bm1,
    float* __restrict__ P, float* __restrict__ Q, int N)
{
    __shared__ __align__(16) short Asub[64 * 40];
    __shared__ __align__(16) short Bsub[256 * 40];
    int tid = threadIdx.x;
    int w = tid >> 6, l = tid & 63;
    int lr = l & 15;            // frag row/col within 16
    int lk = (l >> 4) * 8;      // frag k base
    int n0 = blockIdx.x * 64;

    f32x4 acc[4][4];
    #pragma unroll
    for (int i = 0; i < 4; ++i)
        #pragma unroll
        for (int j = 0; j < 4; ++j) acc[i][j] = (f32x4){0.f, 0.f, 0.f, 0.f};

    int ar = tid >> 2;             // staging row 0..63
    int ac = (tid & 3) * 8;        // chunk offset in k
    int arg = n0 + ar; if (arg > N - 1) arg = N - 1;
    const ushort* bsrc = WC1T + (size_t)tid * 320;   // col = tid

    for (int k0 = 0; k0 < 320; k0 += 32) {
        // ---- stage A: 8 fp32 -> 8 bf16
        int k = k0 + ac;
        const float* asrc;
        if (k < 128)      asrc = s + (size_t)arg * 128 + k;
        else if (k < 256) asrc = x + (size_t)arg * 128 + (k - 128);
        else              asrc = t + (size_t)arg * 64 + (k - 256);
        float4 f0 = *(const float4*)asrc;
        float4 f1 = *(const float4*)(asrc + 4);
        BF8 pk;
        pk.u[0] = f2bf(f0.x); pk.u[1] = f2bf(f0.y); pk.u[2] = f2bf(f0.z); pk.u[3] = f2bf(f0.w);
        pk.u[4] = f2bf(f1.x); pk.u[5] = f2bf(f1.y); pk.u[6] = f2bf(f1.z); pk.u[7] = f2bf(f1.w);
        // ---- stage B: col tid, 4 chunks of 8
        bf16x8 bv0 = *(const bf16x8*)(bsrc + k0);
        bf16x8 bv1 = *(const bf16x8*)(bsrc + k0 + 8);
        bf16x8 bv2 = *(const bf16x8*)(bsrc + k0 + 16);
        bf16x8 bv3 = *(const bf16x8*)(bsrc + k0 + 24);
        __syncthreads();   // previous iteration's frag reads done
        *(bf16x8*)&Asub[ar * 40 + ac] = pk.v;
        *(bf16x8*)&Bsub[tid * 40 + 0]  = bv0;
        *(bf16x8*)&Bsub[tid * 40 + 8]  = bv1;
        *(bf16x8*)&Bsub[tid * 40 + 16] = bv2;
        *(bf16x8*)&Bsub[tid * 40 + 24] = bv3;
        __syncthreads();
        bf16x8 afr[4], bfr[4];
        #pragma unroll
        for (int rt = 0; rt < 4; ++rt) afr[rt] = *(const bf16x8*)&Asub[(rt * 16 + lr) * 40 + lk];
        #pragma unroll
        for (int ct = 0; ct < 4; ++ct) bfr[ct] = *(const bf16x8*)&Bsub[(w * 64 + ct * 16 + lr) * 40 + lk];
        #pragma unroll
        for (int rt = 0; rt < 4; ++rt)
            #pragma unroll
            for (int ct = 0; ct < 4; ++ct)
                acc[rt][ct] = __builtin_amdgcn_mfma_f32_16x16x32_bf16(afr[rt], bfr[ct], acc[rt][ct], 0, 0, 0);
    }

    // epilogue: cols<128 -> P ; cols>=128 -> Q + bm1
    #pragma unroll
    for (int ct = 0; ct < 4; ++ct) {
        int col = w * 64 + ct * 16 + lr;
        float bb = (col >= 128) ? bm1[col - 128] : 0.f;
        #pragma unroll
        for (int rt = 0; rt < 4; ++rt) {
            int rbase = n0 + rt * 16 + (l >> 4) * 4;
            #pragma unroll
            for (int r = 0; r < 4; ++r) {
                int row = rbase + r;
                if (row < N) {
                    float v = acc[rt][ct][r];
                    if (col < 128) P[(size_t)row * 128 + col] = v;
                    else           Q[(size_t)row * 128 + (col - 128)] = v + bb;
                }
            }
        }
    }
}

// ---------------------------------------------------------------------------
// K_agg: segmented reduction over dst-sorted edges. One wave per dst node,
// 2 channels per lane. Outputs GAB (bf16) and SW (fp32). No atomics.
// ---------------------------------------------------------------------------
__global__ __launch_bounds__(256) void k_agg(
    const float* __restrict__ P, const float* __restrict__ Q,
    const int2* __restrict__ rec, const int* __restrict__ offs,
    ushort* __restrict__ GAB, float* __restrict__ sw, int N)
{
    int n = blockIdx.x * 4 + (threadIdx.x >> 6);
    if (n >= N) return;
    int lane = threadIdx.x & 63;
    int beg = offs[n], end = offs[n + 1];
    float2 q = *(const float2*)&Q[(size_t)n * 128 + lane * 2];
    float a0 = 0.f, a1 = 0.f, wsum = 0.f;
    for (int base = beg; base < end; base += 64) {
        int cnt = end - base; if (cnt > 64) cnt = 64;
        int2 r = make_int2(0, 0);
        if (lane < cnt) r = rec[base + lane];
        for (int j = 0; j < cnt; ++j) {
            int  sidx = __shfl(r.x, j);
            float wj  = __int_as_float(__shfl(r.y, j));
            float2 p  = *(const float2*)&P[(size_t)sidx * 128 + lane * 2];
            a0 += wj * gelu_f(p.x + q.x);
            a1 += wj * gelu_f(p.y + q.y);
            wsum += wj;
        }
    }
    ushort2 g2 = make_ushort2(f2bf(a0), f2bf(a1));
    *(ushort2*)&GAB[(size_t)n * 128 + lane * 2] = g2;
    if (lane == 0) sw[n] = wsum;
}

// ---------------------------------------------------------------------------
// K3 (MFMA): fused update MLP.
//   pre2 = [s|agg] @ Wuc + bu1 + sw*BV ; h2 = gelu(pre2) (bf16, LDS)
//   out  = h2 @ Wu2 + bu2
// Block: 256 thr = 4 waves; tile 64 rows x 128 cols; wave w owns cols w*32..+31.
// ---------------------------------------------------------------------------
__global__ __launch_bounds__(256) void k3_mfma(
    const float* __restrict__ s, const ushort* __restrict__ GAB, const float* __restrict__ sw,
    const ushort* __restrict__ WUCT, const float* __restrict__ BV, const float* __restrict__ bu1,
    const ushort* __restrict__ WU2T, const float* __restrict__ bu2,
    float* __restrict__ out, int N)
{
    __shared__ __align__(16) short Asub[64 * 40];
    __shared__ __align__(16) short Bsub[128 * 40];
    __shared__ __align__(16) short H2[64 * 136];
    __shared__ float SWs[64];
    int tid = threadIdx.x;
    int w = tid >> 6, l = tid & 63;
    int lr = l & 15, lk = (l >> 4) * 8;
    int n0 = blockIdx.x * 64;

    if (tid < 64) SWs[tid] = (n0 + tid < N) ? sw[n0 + tid] : 0.f;

    f32x4 acc[4][2];
    #pragma unroll
    for (int i = 0; i < 4; ++i) { acc[i][0] = (f32x4){0,0,0,0}; acc[i][1] = (f32x4){0,0,0,0}; }

    int ar = tid >> 2;
    int ac = (tid & 3) * 8;
    int arg = n0 + ar; if (arg > N - 1) arg = N - 1;
    int bc = tid >> 1;                 // B staging col 0..127
    int bo = (tid & 1) * 16;           // chunk base within 32-k tile

    // Phase A: K = 256
    for (int k0 = 0; k0 < 256; k0 += 32) {
        int k = k0 + ac;
        BF8 pk;
        if (k < 128) {
            const float* asrc = s + (size_t)arg * 128 + k;
            float4 f0 = *(const float4*)asrc;
            float4 f1 = *(const float4*)(asrc + 4);
            pk.u[0] = f2bf(f0.x); pk.u[1] = f2bf(f0.y); pk.u[2] = f2bf(f0.z); pk.u[3] = f2bf(f0.w);
            pk.u[4] = f2bf(f1.x); pk.u[5] = f2bf(f1.y); pk.u[6] = f2bf(f1.z); pk.u[7] = f2bf(f1.w);
        } else {
            pk.v = *(const bf16x8*)(GAB + (size_t)arg * 128 + (k - 128));
        }
        bf16x8 bv0 = *(const bf16x8*)(WUCT + (size_t)bc * 256 + k0 + bo);
        bf16x8 bv1 = *(const bf16x8*)(WUCT + (size_t)bc * 256 + k0 + bo + 8);
        __syncthreads();
        *(bf16x8*)&Asub[ar * 40 + ac] = pk.v;
        *(bf16x8*)&Bsub[bc * 40 + bo]     = bv0;
        *(bf16x8*)&Bsub[bc * 40 + bo + 8] = bv1;
        __syncthreads();
        bf16x8 afr[4], bfr[2];
        #pragma unroll
        for (int rt = 0; rt < 4; ++rt) afr[rt] = *(const bf16x8*)&Asub[(rt * 16 + lr) * 40 + lk];
        #pragma unroll
        for (int ct = 0; ct < 2; ++ct) bfr[ct] = *(const bf16x8*)&Bsub[(w * 32 + ct * 16 + lr) * 40 + lk];
        #pragma unroll
        for (int rt = 0; rt < 4; ++rt)
            #pragma unroll
            for (int ct = 0; ct < 2; ++ct)
                acc[rt][ct] = __builtin_amdgcn_mfma_f32_16x16x32_bf16(afr[rt], bfr[ct], acc[rt][ct], 0, 0, 0);
    }

    // epilogue A: bias + sw*BV, gelu, write bf16 to H2 (transpose-free: h2[row][col])
    #pragma unroll
    for (int ct = 0; ct < 2; ++ct) {
        int col = w * 32 + ct * 16 + lr;
        float b1 = bu1[col], bv = BV[col];
        #pragma unroll
        for (int rt = 0; rt < 4; ++rt) {
            int rbase = rt * 16 + (l >> 4) * 4;
            #pragma unroll
            for (int r = 0; r < 4; ++r) {
                int row = rbase + r;
                float v = acc[rt][ct][r] + b1 + SWs[row] * bv;
                H2[row * 136 + col] = (short)f2bf(gelu_f(v));
            }
        }
    }

    // Phase B: out = h2 @ Wu2 ; K = 128
    f32x4 acc2[4][2];
    #pragma unroll
    for (int i = 0; i < 4; ++i) { acc2[i][0] = (f32x4){0,0,0,0}; acc2[i][1] = (f32x4){0,0,0,0}; }

    for (int k0 = 0; k0 < 128; k0 += 32) {
        bf16x8 bv0 = *(const bf16x8*)(WU2T + (size_t)bc * 128 + k0 + bo);
        bf16x8 bv1 = *(const bf16x8*)(WU2T + (size_t)bc * 128 + k0 + bo + 8);
        __syncthreads();
        *(bf16x8*)&Bsub[bc * 40 + bo]     = bv0;
        *(bf16x8*)&Bsub[bc * 40 + bo + 8] = bv1;
        __syncthreads();
        bf16x8 afr[4], bfr[2];
        #pragma unroll
        for (int rt = 0; rt < 4; ++rt) afr[rt] = *(const bf16x8*)&H2[(rt * 16 + lr) * 136 + k0 + lk];
        #pragma unroll
        for (int ct = 0; ct < 2; ++ct) bfr[ct] = *(const bf16x8*)&Bsub[(w * 32 + ct * 16 + lr) * 40 + lk];
        #pragma unroll
        for (int rt = 0; rt < 4; ++rt)
            #pragma unroll
            for (int ct = 0; ct < 2; ++ct)
                acc2[rt][ct] = __builtin_amdgcn_mfma_f32_16x16x32_bf16(afr[rt], bfr[ct], acc2[rt][ct], 0, 0, 0);
    }

    #pragma unroll
    for (int ct = 0; ct < 2; ++ct) {
        int col = w * 32 + ct * 16 + lr;
        float b2 = bu2[col];
        #pragma unroll
        for (int rt = 0; rt < 4; ++rt) {
            int rbase = n0 + rt * 16 + (l >> 4) * 4;
            #pragma unroll
            for (int r = 0; r < 4; ++r) {
                int row = rbase + r;
                if (row < N) out[(size_t)row * 128 + col] = acc2[rt][ct][r] + b2;
            }
        }
    }
}

// ---------------------------------------------------------------------------
extern "C" void kernel_launch(void* const* d_in, const int* in_sizes, int n_in,
                              void* d_out, int out_size, void* d_ws, size_t ws_size,
                              hipStream_t stream) {
    const float* s    = (const float*)d_in[0];
    const float* x    = (const float*)d_in[1];
    const int*   ei   = (const int*)d_in[2];
    const float* ew   = (const float*)d_in[3];
    const float* t    = (const float*)d_in[4];
    const float* Wm1  = (const float*)d_in[5];
    const float* bm1  = (const float*)d_in[6];
    const float* Wm2  = (const float*)d_in[7];
    const float* bm2  = (const float*)d_in[8];
    const float* Wu1  = (const float*)d_in[9];
    const float* bu1  = (const float*)d_in[10];
    const float* Wu2  = (const float*)d_in[11];
    const float* bu2  = (const float*)d_in[12];

    int N = in_sizes[0] / 128;
    int E = in_sizes[2] / 2;
    const int* srcI = ei;
    const int* dstI = ei + E;

    // workspace layout (32-bit words); ~72 MB total
    float* ws = (float*)d_ws;
    size_t off = 0;
    float*  P    = ws + off; off += (size_t)N * 128;
    float*  Q    = ws + off; off += (size_t)N * 128;
    float*  SW   = ws + off; off += ((size_t)N + 63) & ~(size_t)63;
    ushort* GAB  = (ushort*)(ws + off); off += (size_t)N * 64;          // N*128 bf16
    ushort* WC1T = (ushort*)(ws + off); off += (256 * 320) / 2;
    ushort* WUCT = (ushort*)(ws + off); off += (128 * 256) / 2;
    ushort* WU2T = (ushort*)(ws + off); off += (128 * 128) / 2;
    float*  BV   = ws + off; off += 128;
    int*    DEG  = (int*)(ws + off); off += (size_t)N;
    int*    OFFS = (int*)(ws + off); off += (size_t)N + 64;
    int*    CUR  = (int*)(ws + off); off += (size_t)N;
    off = (off + 1) & ~(size_t)1;
    int2*   REC  = (int2*)(ws + off); off += (size_t)E * 2;

    // weight prep
    k_build_wc1t<<<(256 * 320) / 256, 256, 0, stream>>>(Wm1, WC1T);
    k_build_wuct<<<(128 * 256) / 256, 256, 0, stream>>>(Wu1, Wm2, bm2, WUCT, BV);
    k_build_wu2t<<<(128 * 128) / 256, 256, 0, stream>>>(Wu2, WU2T);

    // counting sort by dst
    k_zero_i<<<(N + 255) / 256, 256, 0, stream>>>(DEG, N);
    k_hist<<<(E + 255) / 256, 256, 0, stream>>>(dstI, DEG, E);
    k_scan<<<1, 1024, 0, stream>>>(DEG, OFFS, CUR, N, E);
    k_scatter<<<(E + 255) / 256, 256, 0, stream>>>(srcI, dstI, ew, CUR, REC, E);

    // node precompute (MFMA)
    int nb = (N + 63) / 64;
    k1_mfma<<<nb, 256, 0, stream>>>(s, x, t, WC1T, bm1, P, Q, N);

    // segmented aggregation
    k_agg<<<(N + 3) / 4, 256, 0, stream>>>(P, Q, REC, OFFS, GAB, SW, N);

    // update MLP (MFMA, fused)
    k3_mfma<<<nb, 256, 0, stream>>>(s, GAB, SW, WUCT, BV, bu1, WU2T, bu2, (float*)d_out, N);
}

// Round 4
// 274.273 us; speedup vs baseline: 3.5141x; 1.1150x over previous
//
#include <hip/hip_runtime.h>
#include <math.h>

// Problem constants
#define NHID 128

typedef __attribute__((ext_vector_type(8))) short bf16x8;
typedef __attribute__((ext_vector_type(4))) float f32x4;

union BF8 { ushort u[8]; bf16x8 v; };

__device__ __forceinline__ ushort f2bf(float f) {
    unsigned int u = __float_as_uint(f);
    u += 0x7FFFu + ((u >> 16) & 1u);      // round-to-nearest-even
    return (ushort)(u >> 16);
}

// Branch-free GELU (exact-erf form via Abramowitz-Stegun 7.1.26, max err ~1.5e-7)
// gelu(x) = 0.5*(x+|x|) - 0.5*|x| * P(t) * exp(-x^2/2),  t = 1/(1+0.2316549*|x|)
__device__ __forceinline__ float gelu_fast(float x) {
    float ax = fabsf(x);
    float t  = __builtin_amdgcn_rcpf(fmaf(0.23165493f, ax, 1.0f));
    float p  = t * fmaf(t, fmaf(t, fmaf(t, fmaf(t, 1.061405429f, -1.453152027f),
                                        1.421413741f), -0.284496736f), 0.254829592f);
    float e  = __builtin_amdgcn_exp2f(-0.7213475204f * ax * ax);
    float hax = 0.5f * ax;
    return fmaf(-hax, p * e, 0.5f * x + hax);
}

// ---------------------------------------------------------------------------
// Weight prep: bf16, TRANSPOSED to [col][k] so MFMA B-frags are contiguous-8.
// WC1T [256 cols][320 k]: combined first layer.
// ---------------------------------------------------------------------------
__global__ void k_build_wc1t(const float* __restrict__ Wm1, ushort* __restrict__ WC1T) {
    int idx = blockIdx.x * blockDim.x + threadIdx.x;   // 256*320
    int c = idx / 320, k = idx % 320;
    float v;
    if (k < 128) {
        v = (c < 128) ? Wm1[k * 128 + c] : Wm1[(128 + k) * 128 + (c - 128)];
    } else if (k < 256) {
        int kk = k - 128;
        v = (c < 128) ? Wm1[(256 + kk) * 128 + c] : -Wm1[(256 + kk) * 128 + (c - 128)];
    } else {
        int kk = k - 256;
        v = (c < 128) ? 0.0f : Wm1[(384 + kk) * 128 + (c - 128)];
    }
    WC1T[idx] = f2bf(v);
}

// WUCT [128 cols][256 k]; BV[c] = bm2 @ Wu1_bot
__global__ void k_build_wuct(const float* __restrict__ Wu1, const float* __restrict__ Wm2,
                             const float* __restrict__ bm2, ushort* __restrict__ WUCT,
                             float* __restrict__ BV) {
    int idx = blockIdx.x * blockDim.x + threadIdx.x;   // 128*256
    int c = idx >> 8, k = idx & 255;
    float v;
    if (k < 128) {
        v = Wu1[k * 128 + c];
    } else {
        int i = k - 128;
        float acc = 0.f;
        for (int j = 0; j < 128; ++j) acc += Wm2[i * 128 + j] * Wu1[(128 + j) * 128 + c];
        v = acc;
    }
    WUCT[idx] = f2bf(v);
    if (idx < 128) {
        float acc = 0.f;
        for (int j = 0; j < 128; ++j) acc += bm2[j] * Wu1[(128 + j) * 128 + idx];
        BV[idx] = acc;
    }
}

__global__ void k_build_wu2t(const float* __restrict__ Wu2, ushort* __restrict__ WU2T) {
    int idx = blockIdx.x * blockDim.x + threadIdx.x;   // 128*128
    int c = idx >> 7, k = idx & 127;
    WU2T[idx] = f2bf(Wu2[k * 128 + c]);
}

// ---------------------------------------------------------------------------
// Counting-sort pipeline
// ---------------------------------------------------------------------------
__global__ void k_zero_i(int* __restrict__ p, int n) {
    int i = blockIdx.x * blockDim.x + threadIdx.x;
    if (i < n) p[i] = 0;
}
__global__ void k_hist(const int* __restrict__ dst, int* __restrict__ deg, int E) {
    int i = blockIdx.x * blockDim.x + threadIdx.x;
    if (i < E) atomicAdd(&deg[dst[i]], 1);
}
__global__ __launch_bounds__(1024) void k_scan(const int* __restrict__ deg,
                                               int* __restrict__ offs,
                                               int* __restrict__ cursor, int N, int E) {
    __shared__ int wsum[17];
    int tid = threadIdx.x;
    int lane = tid & 63, wid = tid >> 6;
    if (tid == 0) wsum[16] = 0;
    __syncthreads();
    for (int base = 0; base < N; base += 1024) {
        int i = base + tid;
        int v = (i < N) ? deg[i] : 0;
        int incl = v;
        #pragma unroll
        for (int d = 1; d < 64; d <<= 1) {
            int t = __shfl_up(incl, d);
            if (lane >= d) incl += t;
        }
        if (lane == 63) wsum[wid] = incl;
        __syncthreads();
        if (tid == 0) {
            int run = wsum[16];
            #pragma unroll
            for (int k = 0; k < 16; ++k) { int t = wsum[k]; wsum[k] = run; run += t; }
            wsum[16] = run;
        }
        __syncthreads();
        int excl = wsum[wid] + incl - v;
        if (i < N) { offs[i] = excl; cursor[i] = excl; }
        __syncthreads();
    }
    if (tid == 0) offs[N] = E;
}
__global__ void k_scatter(const int* __restrict__ src, const int* __restrict__ dst,
                          const float* __restrict__ w, int* __restrict__ cursor,
                          int2* __restrict__ rec, int E) {
    int i = blockIdx.x * blockDim.x + threadIdx.x;
    if (i < E) {
        int d = dst[i];
        int pos = atomicAdd(&cursor[d], 1);
        rec[pos] = make_int2(src[i], __float_as_int(w[i]));
    }
}

// ---------------------------------------------------------------------------
// K1 (MFMA): [P|Q] = [s|x|t] @ Wc1.  P stored bf16 (gather operand), Q fp32.
// ---------------------------------------------------------------------------
__global__ __launch_bounds__(256) void k1_mfma(
    const float* __restrict__ s, const float* __restrict__ x, const float* __restrict__ t,
    const ushort* __restrict__ WC1T, const float* __restrict__ bm1,
    ushort* __restrict__ Pb, float* __restrict__ Q, int N)
{
    __shared__ __align__(16) short Asub[64 * 40];
    __shared__ __align__(16) short Bsub[256 * 40];
    int tid = threadIdx.x;
    int w = tid >> 6, l = tid & 63;
    int lr = l & 15;
    int lk = (l >> 4) * 8;
    int n0 = blockIdx.x * 64;

    f32x4 acc[4][4];
    #pragma unroll
    for (int i = 0; i < 4; ++i)
        #pragma unroll
        for (int j = 0; j < 4; ++j) acc[i][j] = (f32x4){0.f, 0.f, 0.f, 0.f};

    int ar = tid >> 2;
    int ac = (tid & 3) * 8;
    int arg = n0 + ar; if (arg > N - 1) arg = N - 1;
    const ushort* bsrc = WC1T + (size_t)tid * 320;

    for (int k0 = 0; k0 < 320; k0 += 32) {
        int k = k0 + ac;
        const float* asrc;
        if (k < 128)      asrc = s + (size_t)arg * 128 + k;
        else if (k < 256) asrc = x + (size_t)arg * 128 + (k - 128);
        else              asrc = t + (size_t)arg * 64 + (k - 256);
        float4 f0 = *(const float4*)asrc;
        float4 f1 = *(const float4*)(asrc + 4);
        BF8 pk;
        pk.u[0] = f2bf(f0.x); pk.u[1] = f2bf(f0.y); pk.u[2] = f2bf(f0.z); pk.u[3] = f2bf(f0.w);
        pk.u[4] = f2bf(f1.x); pk.u[5] = f2bf(f1.y); pk.u[6] = f2bf(f1.z); pk.u[7] = f2bf(f1.w);
        bf16x8 bv0 = *(const bf16x8*)(bsrc + k0);
        bf16x8 bv1 = *(const bf16x8*)(bsrc + k0 + 8);
        bf16x8 bv2 = *(const bf16x8*)(bsrc + k0 + 16);
        bf16x8 bv3 = *(const bf16x8*)(bsrc + k0 + 24);
        __syncthreads();
        *(bf16x8*)&Asub[ar * 40 + ac] = pk.v;
        *(bf16x8*)&Bsub[tid * 40 + 0]  = bv0;
        *(bf16x8*)&Bsub[tid * 40 + 8]  = bv1;
        *(bf16x8*)&Bsub[tid * 40 + 16] = bv2;
        *(bf16x8*)&Bsub[tid * 40 + 24] = bv3;
        __syncthreads();
        bf16x8 afr[4], bfr[4];
        #pragma unroll
        for (int rt = 0; rt < 4; ++rt) afr[rt] = *(const bf16x8*)&Asub[(rt * 16 + lr) * 40 + lk];
        #pragma unroll
        for (int ct = 0; ct < 4; ++ct) bfr[ct] = *(const bf16x8*)&Bsub[(w * 64 + ct * 16 + lr) * 40 + lk];
        #pragma unroll
        for (int rt = 0; rt < 4; ++rt)
            #pragma unroll
            for (int ct = 0; ct < 4; ++ct)
                acc[rt][ct] = __builtin_amdgcn_mfma_f32_16x16x32_bf16(afr[rt], bfr[ct], acc[rt][ct], 0, 0, 0);
    }

    #pragma unroll
    for (int ct = 0; ct < 4; ++ct) {
        int col = w * 64 + ct * 16 + lr;
        float bb = (col >= 128) ? bm1[col - 128] : 0.f;
        #pragma unroll
        for (int rt = 0; rt < 4; ++rt) {
            int rbase = n0 + rt * 16 + (l >> 4) * 4;
            #pragma unroll
            for (int r = 0; r < 4; ++r) {
                int row = rbase + r;
                if (row < N) {
                    float v = acc[rt][ct][r];
                    if (col < 128) Pb[(size_t)row * 128 + col] = f2bf(v);
                    else           Q[(size_t)row * 128 + (col - 128)] = v + bb;
                }
            }
        }
    }
}

// ---------------------------------------------------------------------------
// K_agg: segmented reduction over dst-sorted edges. One wave per dst node,
// 2 channels per lane. readlane broadcast (scalar pipe), bf16 P gathers,
// branch-free gelu, 2-way unrolled edge loop. No atomics.
// ---------------------------------------------------------------------------
__global__ __launch_bounds__(256) void k_agg(
    const ushort* __restrict__ Pb, const float* __restrict__ Q,
    const int2* __restrict__ rec, const int* __restrict__ offs,
    ushort* __restrict__ GAB, float* __restrict__ sw, int N)
{
    int n = blockIdx.x * 4 + (threadIdx.x >> 6);
    if (n >= N) return;
    int lane = threadIdx.x & 63;
    int beg = offs[n], end = offs[n + 1];
    float2 q = *(const float2*)&Q[(size_t)n * 128 + lane * 2];
    float a0 = 0.f, a1 = 0.f, wsum = 0.f;
    for (int base = beg; base < end; base += 64) {
        int cnt = end - base; if (cnt > 64) cnt = 64;
        int2 r = make_int2(0, 0);
        if (lane < cnt) r = rec[base + lane];
        int j = 0;
        for (; j + 1 < cnt; j += 2) {
            int   s0 = __builtin_amdgcn_readlane(r.x, j);
            float w0 = __int_as_float(__builtin_amdgcn_readlane(r.y, j));
            int   s1 = __builtin_amdgcn_readlane(r.x, j + 1);
            float w1 = __int_as_float(__builtin_amdgcn_readlane(r.y, j + 1));
            unsigned int p0 = *(const unsigned int*)&Pb[(size_t)s0 * 128 + lane * 2];
            unsigned int p1 = *(const unsigned int*)&Pb[(size_t)s1 * 128 + lane * 2];
            float p0x = __uint_as_float(p0 << 16);
            float p0y = __uint_as_float(p0 & 0xffff0000u);
            float p1x = __uint_as_float(p1 << 16);
            float p1y = __uint_as_float(p1 & 0xffff0000u);
            a0 = fmaf(w0, gelu_fast(p0x + q.x), a0);
            a1 = fmaf(w0, gelu_fast(p0y + q.y), a1);
            a0 = fmaf(w1, gelu_fast(p1x + q.x), a0);
            a1 = fmaf(w1, gelu_fast(p1y + q.y), a1);
            wsum += w0 + w1;
        }
        if (j < cnt) {
            int   s0 = __builtin_amdgcn_readlane(r.x, j);
            float w0 = __int_as_float(__builtin_amdgcn_readlane(r.y, j));
            unsigned int p0 = *(const unsigned int*)&Pb[(size_t)s0 * 128 + lane * 2];
            float p0x = __uint_as_float(p0 << 16);
            float p0y = __uint_as_float(p0 & 0xffff0000u);
            a0 = fmaf(w0, gelu_fast(p0x + q.x), a0);
            a1 = fmaf(w0, gelu_fast(p0y + q.y), a1);
            wsum += w0;
        }
    }
    ushort2 g2 = make_ushort2(f2bf(a0), f2bf(a1));
    *(ushort2*)&GAB[(size_t)n * 128 + lane * 2] = g2;
    if (lane == 0) sw[n] = wsum;
}

// ---------------------------------------------------------------------------
// K3 (MFMA): fused update MLP.
// ---------------------------------------------------------------------------
__global__ __launch_bounds__(256) void k3_mfma(
    const float* __restrict__ s, const ushort* __restrict__ GAB, const float* __restrict__ sw,
    const ushort* __restrict__ WUCT, const float* __restrict__ BV, const float* __restrict__ bu1,
    const ushort* __restrict__ WU2T, const float* __restrict__ bu2,
    float* __restrict__ out, int N)
{
    __shared__ __align__(16) short Asub[64 * 40];
    __shared__ __align__(16) short Bsub[128 * 40];
    __shared__ __align__(16) short H2[64 * 136];
    __shared__ float SWs[64];
    int tid = threadIdx.x;
    int w = tid >> 6, l = tid & 63;
    int lr = l & 15, lk = (l >> 4) * 8;
    int n0 = blockIdx.x * 64;

    if (tid < 64) SWs[tid] = (n0 + tid < N) ? sw[n0 + tid] : 0.f;

    f32x4 acc[4][2];
    #pragma unroll
    for (int i = 0; i < 4; ++i) { acc[i][0] = (f32x4){0,0,0,0}; acc[i][1] = (f32x4){0,0,0,0}; }

    int ar = tid >> 2;
    int ac = (tid & 3) * 8;
    int arg = n0 + ar; if (arg > N - 1) arg = N - 1;
    int bc = tid >> 1;
    int bo = (tid & 1) * 16;

    for (int k0 = 0; k0 < 256; k0 += 32) {
        int k = k0 + ac;
        BF8 pk;
        if (k < 128) {
            const float* asrc = s + (size_t)arg * 128 + k;
            float4 f0 = *(const float4*)asrc;
            float4 f1 = *(const float4*)(asrc + 4);
            pk.u[0] = f2bf(f0.x); pk.u[1] = f2bf(f0.y); pk.u[2] = f2bf(f0.z); pk.u[3] = f2bf(f0.w);
            pk.u[4] = f2bf(f1.x); pk.u[5] = f2bf(f1.y); pk.u[6] = f2bf(f1.z); pk.u[7] = f2bf(f1.w);
        } else {
            pk.v = *(const bf16x8*)(GAB + (size_t)arg * 128 + (k - 128));
        }
        bf16x8 bv0 = *(const bf16x8*)(WUCT + (size_t)bc * 256 + k0 + bo);
        bf16x8 bv1 = *(const bf16x8*)(WUCT + (size_t)bc * 256 + k0 + bo + 8);
        __syncthreads();
        *(bf16x8*)&Asub[ar * 40 + ac] = pk.v;
        *(bf16x8*)&Bsub[bc * 40 + bo]     = bv0;
        *(bf16x8*)&Bsub[bc * 40 + bo + 8] = bv1;
        __syncthreads();
        bf16x8 afr[4], bfr[2];
        #pragma unroll
        for (int rt = 0; rt < 4; ++rt) afr[rt] = *(const bf16x8*)&Asub[(rt * 16 + lr) * 40 + lk];
        #pragma unroll
        for (int ct = 0; ct < 2; ++ct) bfr[ct] = *(const bf16x8*)&Bsub[(w * 32 + ct * 16 + lr) * 40 + lk];
        #pragma unroll
        for (int rt = 0; rt < 4; ++rt)
            #pragma unroll
            for (int ct = 0; ct < 2; ++ct)
                acc[rt][ct] = __builtin_amdgcn_mfma_f32_16x16x32_bf16(afr[rt], bfr[ct], acc[rt][ct], 0, 0, 0);
    }

    #pragma unroll
    for (int ct = 0; ct < 2; ++ct) {
        int col = w * 32 + ct * 16 + lr;
        float b1 = bu1[col], bv = BV[col];
        #pragma unroll
        for (int rt = 0; rt < 4; ++rt) {
            int rbase = rt * 16 + (l >> 4) * 4;
            #pragma unroll
            for (int r = 0; r < 4; ++r) {
                int row = rbase + r;
                float v = acc[rt][ct][r] + b1 + SWs[row] * bv;
                H2[row * 136 + col] = (short)f2bf(gelu_fast(v));
            }
        }
    }

    f32x4 acc2[4][2];
    #pragma unroll
    for (int i = 0; i < 4; ++i) { acc2[i][0] = (f32x4){0,0,0,0}; acc2[i][1] = (f32x4){0,0,0,0}; }

    for (int k0 = 0; k0 < 128; k0 += 32) {
        bf16x8 bv0 = *(const bf16x8*)(WU2T + (size_t)bc * 128 + k0 + bo);
        bf16x8 bv1 = *(const bf16x8*)(WU2T + (size_t)bc * 128 + k0 + bo + 8);
        __syncthreads();
        *(bf16x8*)&Bsub[bc * 40 + bo]     = bv0;
        *(bf16x8*)&Bsub[bc * 40 + bo + 8] = bv1;
        __syncthreads();
        bf16x8 afr[4], bfr[2];
        #pragma unroll
        for (int rt = 0; rt < 4; ++rt) afr[rt] = *(const bf16x8*)&H2[(rt * 16 + lr) * 136 + k0 + lk];
        #pragma unroll
        for (int ct = 0; ct < 2; ++ct) bfr[ct] = *(const bf16x8*)&Bsub[(w * 32 + ct * 16 + lr) * 40 + lk];
        #pragma unroll
        for (int rt = 0; rt < 4; ++rt)
            #pragma unroll
            for (int ct = 0; ct < 2; ++ct)
                acc2[rt][ct] = __builtin_amdgcn_mfma_f32_16x16x32_bf16(afr[rt], bfr[ct], acc2[rt][ct], 0, 0, 0);
    }

    #pragma unroll
    for (int ct = 0; ct < 2; ++ct) {
        int col = w * 32 + ct * 16 + lr;
        float b2 = bu2[col];
        #pragma unroll
        for (int rt = 0; rt < 4; ++rt) {
            int rbase = n0 + rt * 16 + (l >> 4) * 4;
            #pragma unroll
            for (int r = 0; r < 4; ++r) {
                int row = rbase + r;
                if (row < N) out[(size_t)row * 128 + col] = acc2[rt][ct][r] + b2;
            }
        }
    }
}

// ---------------------------------------------------------------------------
extern "C" void kernel_launch(void* const* d_in, const int* in_sizes, int n_in,
                              void* d_out, int out_size, void* d_ws, size_t ws_size,
                              hipStream_t stream) {
    const float* s    = (const float*)d_in[0];
    const float* x    = (const float*)d_in[1];
    const int*   ei   = (const int*)d_in[2];
    const float* ew   = (const float*)d_in[3];
    const float* t    = (const float*)d_in[4];
    const float* Wm1  = (const float*)d_in[5];
    const float* bm1  = (const float*)d_in[6];
    const float* Wm2  = (const float*)d_in[7];
    const float* bm2  = (const float*)d_in[8];
    const float* Wu1  = (const float*)d_in[9];
    const float* bu1  = (const float*)d_in[10];
    const float* Wu2  = (const float*)d_in[11];
    const float* bu2  = (const float*)d_in[12];

    int N = in_sizes[0] / 128;
    int E = in_sizes[2] / 2;
    const int* srcI = ei;
    const int* dstI = ei + E;

    // workspace layout (32-bit words)
    float* ws = (float*)d_ws;
    size_t off = 0;
    ushort* Pb   = (ushort*)(ws + off); off += (size_t)N * 64;          // N*128 bf16
    float*  Q    = ws + off; off += (size_t)N * 128;
    float*  SW   = ws + off; off += ((size_t)N + 63) & ~(size_t)63;
    ushort* GAB  = (ushort*)(ws + off); off += (size_t)N * 64;          // N*128 bf16
    ushort* WC1T = (ushort*)(ws + off); off += (256 * 320) / 2;
    ushort* WUCT = (ushort*)(ws + off); off += (128 * 256) / 2;
    ushort* WU2T = (ushort*)(ws + off); off += (128 * 128) / 2;
    float*  BV   = ws + off; off += 128;
    int*    DEG  = (int*)(ws + off); off += (size_t)N;
    int*    OFFS = (int*)(ws + off); off += (size_t)N + 64;
    int*    CUR  = (int*)(ws + off); off += (size_t)N;
    off = (off + 1) & ~(size_t)1;
    int2*   REC  = (int2*)(ws + off); off += (size_t)E * 2;

    // weight prep
    k_build_wc1t<<<(256 * 320) / 256, 256, 0, stream>>>(Wm1, WC1T);
    k_build_wuct<<<(128 * 256) / 256, 256, 0, stream>>>(Wu1, Wm2, bm2, WUCT, BV);
    k_build_wu2t<<<(128 * 128) / 256, 256, 0, stream>>>(Wu2, WU2T);

    // counting sort by dst
    k_zero_i<<<(N + 255) / 256, 256, 0, stream>>>(DEG, N);
    k_hist<<<(E + 255) / 256, 256, 0, stream>>>(dstI, DEG, E);
    k_scan<<<1, 1024, 0, stream>>>(DEG, OFFS, CUR, N, E);
    k_scatter<<<(E + 255) / 256, 256, 0, stream>>>(srcI, dstI, ew, CUR, REC, E);

    // node precompute (MFMA)
    int nb = (N + 63) / 64;
    k1_mfma<<<nb, 256, 0, stream>>>(s, x, t, WC1T, bm1, Pb, Q, N);

    // segmented aggregation
    k_agg<<<(N + 3) / 4, 256, 0, stream>>>(Pb, Q, REC, OFFS, GAB, SW, N);

    // update MLP (MFMA, fused)
    k3_mfma<<<nb, 256, 0, stream>>>(s, GAB, SW, WUCT, BV, bu1, WU2T, bu2, (float*)d_out, N);
}